// Round 9
// baseline (119.249 us; speedup 1.0000x reference)
//
#include <hip/hip_runtime.h>

// Problem constants
#define DD 20          // hypervol spatial extent per axis
#define MM 32          // channel count m
#define OO 19          // output extent per axis (DD - RANK + 1, RANK=2)
#define NWIN (OO*OO*OO)                  // 6859 windows
#define WPB 4                            // windows per block (one per wave)
#define NBLK ((NWIN + WPB - 1) / WPB)    // 1715 blocks

// Lane tiling (phases 2/3): lane -> h = lane>>5 (j-half), i = lane&31 (own
// output channel), ib = lane&28 (i-quad base), qd = lane&3 (j-quad in half).
// Each lane owns a 4x4 tile: i' = ib+r (r=0..3), j' = h*16 + qd*4 + e (e=0..3).
// Tables stored so each (k,r) is one coalesced 1KB float4 load:
//   CS[k][r][lane][e] = cos(2*pi*k / (i'*32 + j' + 2))
//   PS[r][lane][e]    = P [i'][j']
//   MS[r][lane][e]    = Mw[i'][j'] / 16
#define CS_FLOATS (OO*MM*MM)             // 19456
#define PS_OFF CS_FLOATS                 // 19456 (= 19*1024)
#define MS_OFF (PS_OFF + MM*MM)          // 20480 (= 20*1024)
#define WS_FLOATS (MS_OFF + MM*MM)       // 21504

// per-wave LDS slice: S (640 floats) + X (608 floats), no aliasing
#define LSLICE 1248
#define XOFF 640

__global__ __launch_bounds__(256) void build_tables_kernel(
        const float* __restrict__ Mw, const float* __restrict__ P,
        float* __restrict__ ws) {
    const int idx = blockIdx.x * 256 + threadIdx.x;
    if (idx >= WS_FLOATS) return;
    const int r10  = idx & 1023;         // PS_OFF/MS_OFF are multiples of 1024
    const int r    = r10 >> 8;
    const int lane = (r10 >> 2) & 63;
    const int e    = r10 & 3;
    const int ii   = (lane & 28) + r;
    const int jj   = ((lane >> 5) << 4) + (lane & 3) * 4 + e;
    if (idx < CS_FLOATS) {
        const int k = idx >> 10;
        ws[idx] = cosf(6.28318530717958647692f * (float)k
                       / (float)(ii * MM + jj + 2));
    } else if (idx < MS_OFF) {
        ws[idx] = P[ii * MM + jj];
    } else {
        ws[idx] = Mw[ii * MM + jj] * 0.0625f;
    }
}

// Wave-internal sync: LDS-counter drain only + compiler fence.
__device__ __forceinline__ void lds_sync() {
    __builtin_amdgcn_s_waitcnt(0xC07F);   // lgkmcnt(0) only
    __builtin_amdgcn_wave_barrier();
}

// DPP quad_perm helpers (VALU pipe, not LDS): xor1 = [1,0,3,2], xor2 = [2,3,0,1]
template <int CTRL>
__device__ __forceinline__ float fdpp(float v) {
    return __int_as_float(__builtin_amdgcn_update_dpp(
        0, __float_as_int(v), CTRL, 0xF, 0xF, true));
}
__device__ __forceinline__ float quad_sum(float v) {
    v += fdpp<0xB1>(v);   // + lane^1
    v += fdpp<0x4E>(v);   // + lane^2
    return v;             // all 4 lanes of the quad hold the quad total
}

// One WAVE per (a,b,c) window; 4 independent windows per block.
// Phase 3: Chebyshev recurrence s_d = 2cosw*s_{d-1} - s_{d-2}, qp in init.
// (256,4): phase 3 carries 64 persistent VGPRs of state; (256,5) spills (R6).
__global__ __launch_bounds__(256, 4) void spatial_kernel(
        const float* __restrict__ H, const float* __restrict__ ws,
        float* __restrict__ out) {
    __shared__ __align__(16) float sLDS[WPB][LSLICE];

    const int tid  = threadIdx.x;
    const int w    = tid >> 6;
    const int lane = tid & 63;
    const int i    = lane & 31;
    const int h    = lane >> 5;
    const int qd   = lane & 3;
    const int jb2  = (h << 4) + qd * 4;   // lane's j-quad base

    // XCD-contiguous block swizzle (1715 = 3*215 + 5*214, bijective)
    const int raw = blockIdx.x;
    const int xcd = raw & 7;
    const int k   = raw >> 3;
    const int sb  = (xcd < 3) ? (xcd * 215 + k) : (645 + (xcd - 3) * 214 + k);
    const int win = sb * WPB + w;
    if (win >= NWIN) return;             // wave-uniform; no block barriers exist
    const int c = win % OO;
    const int b = (win / OO) % OO;
    const int a = win / (OO * OO);

    const float4* __restrict__ T = (const float4*)ws;
    float* __restrict__ S = sLDS[w];          // phase-1 pre-sums (640 floats)
    float* __restrict__ X = sLDS[w] + XOFF;   // x rows           (608 floats)

    // ---- table loads + Chebyshev/state init (in flight alongside H loads) ----
    float4 mt[4], s0[4], s1[4], t2c[4];
    #pragma unroll
    for (int r = 0; r < 4; ++r) {
        const float4 pv = T[(PS_OFF >> 2) + r * 64 + lane];
        const float4 va = T[(a * 4 + r) * 64 + lane];
        const float4 vb = T[(b * 4 + r) * 64 + lane];
        const float4 vc = T[(c * 4 + r) * 64 + lane];
        const float4 c1 = T[(1 * 4 + r) * 64 + lane];
        mt[r] = T[(MS_OFF >> 2) + r * 64 + lane];
        float4 qp;
        qp.x = pv.x * va.x * vb.x * vc.x;
        qp.y = pv.y * va.y * vb.y * vc.y;
        qp.z = pv.z * va.z * vb.z * vc.z;
        qp.w = pv.w * va.w * vb.w * vc.w;
        s1[r] = qp;
        s0[r] = make_float4(qp.x * c1.x, qp.y * c1.y, qp.z * c1.z, qp.w * c1.w);
        t2c[r] = make_float4(c1.x + c1.x, c1.y + c1.y, c1.z + c1.z, c1.w + c1.w);
    }

    // ---- phase 1: 8-shift (a,b,c) pre-sum, 640 floats, float4 ----
    {
        float4 a0 = make_float4(0.f, 0.f, 0.f, 0.f);
        float4 a1 = a0, a2 = a0;
        #pragma unroll
        for (int da = 0; da < 2; ++da)
            #pragma unroll
            for (int db = 0; db < 2; ++db)
                #pragma unroll
                for (int dc = 0; dc < 2; ++dc) {
                    const float4* __restrict__ p = (const float4*)(
                        H + (size_t)((((a + da) * DD + (b + db)) * DD + (c + dc)) * DD) * MM);
                    const float4 v0 = p[lane];
                    const float4 v1 = p[64 + lane];
                    a0.x += v0.x; a0.y += v0.y; a0.z += v0.z; a0.w += v0.w;
                    a1.x += v1.x; a1.y += v1.y; a1.z += v1.z; a1.w += v1.w;
                    if (lane < 32) {
                        const float4 v2 = p[128 + lane];
                        a2.x += v2.x; a2.y += v2.y; a2.z += v2.z; a2.w += v2.w;
                    }
                }
        ((float4*)S)[lane]      = a0;
        ((float4*)S)[64 + lane] = a1;
        if (lane < 32) ((float4*)S)[128 + lane] = a2;
    }
    lds_sync();

    // ---- phase 2: y[d'] = S[d'] . (M/16) per 4x4 tile; x[d] = y[d]+y[d+1] ----
    // One ds_read_b128 per d' (8 distinct addrs/wave); quad combine via DPP.
    {
        float yprev = 0.f;
        #pragma unroll
        for (int dp = 0; dp < DD; ++dp) {
            const float4 sv = *(const float4*)(S + dp * MM + jb2);
            float p0 = sv.x*mt[0].x + sv.y*mt[0].y + sv.z*mt[0].z + sv.w*mt[0].w;
            float p1 = sv.x*mt[1].x + sv.y*mt[1].y + sv.z*mt[1].z + sv.w*mt[1].w;
            float p2 = sv.x*mt[2].x + sv.y*mt[2].y + sv.z*mt[2].z + sv.w*mt[2].w;
            float p3 = sv.x*mt[3].x + sv.y*mt[3].y + sv.z*mt[3].z + sv.w*mt[3].w;
            const float q0 = quad_sum(p0), q1 = quad_sum(p1);
            const float q2 = quad_sum(p2), q3 = quad_sum(p3);
            const float yv = (qd & 1) ? ((qd & 2) ? q3 : q1)
                                      : ((qd & 2) ? q2 : q0);   // this lane's i
            if (dp > 0) {
                float xd = yprev + yv;            // half-sum over lane's h
                xd += __shfl_xor(xd, 32, 64);     // combine halves
                if (h == 0) X[(dp - 1) * MM + i] = xd;
            }
            yprev = yv;
        }
    }
    lds_sync();

    // ---- phase 3: out[d][i] = sum_j x[d][j]*qp[i][j]*cos(w_ij*d) ----
    const size_t obase = (size_t)win * (OO * MM);
    #pragma unroll
    for (int d = 0; d < OO; ++d) {
        const float4 xv = *(const float4*)(X + d * MM + jb2);   // 1 b128/lane
        float p0 = xv.x*s1[0].x + xv.y*s1[0].y + xv.z*s1[0].z + xv.w*s1[0].w;
        float p1 = xv.x*s1[1].x + xv.y*s1[1].y + xv.z*s1[1].z + xv.w*s1[1].w;
        float p2 = xv.x*s1[2].x + xv.y*s1[2].y + xv.z*s1[2].z + xv.w*s1[2].w;
        float p3 = xv.x*s1[3].x + xv.y*s1[3].y + xv.z*s1[3].z + xv.w*s1[3].w;
        #pragma unroll
        for (int r = 0; r < 4; ++r) {            // advance recurrence (16 FMA)
            float4 ns;
            ns.x = __builtin_fmaf(t2c[r].x, s1[r].x, -s0[r].x);
            ns.y = __builtin_fmaf(t2c[r].y, s1[r].y, -s0[r].y);
            ns.z = __builtin_fmaf(t2c[r].z, s1[r].z, -s0[r].z);
            ns.w = __builtin_fmaf(t2c[r].w, s1[r].w, -s0[r].w);
            s0[r] = s1[r];
            s1[r] = ns;
        }
        const float q0 = quad_sum(p0), q1 = quad_sum(p1);
        const float q2 = quad_sum(p2), q3 = quad_sum(p3);
        float t = (qd & 1) ? ((qd & 2) ? q3 : q1)
                           : ((qd & 2) ? q2 : q0);
        t += __shfl_xor(t, 32, 64);
        if (h == 0) out[obase + d * MM + i] = t;
    }
}

extern "C" void kernel_launch(void* const* d_in, const int* in_sizes, int n_in,
                              void* d_out, int out_size, void* d_ws, size_t ws_size,
                              hipStream_t stream) {
    const float* H  = (const float*)d_in[0];   // hypervol [20,20,20,20,32]
    const float* Mw = (const float*)d_in[1];   // M_w [32,32]
    const float* P  = (const float*)d_in[2];   // P   [32,32]
    float* out = (float*)d_out;
    float* ws  = (float*)d_ws;

    build_tables_kernel<<<(WS_FLOATS + 255) / 256, 256, 0, stream>>>(Mw, P, ws);
    spatial_kernel<<<NBLK, 256, 0, stream>>>(H, ws, out);
}

// Round 10
// 102.430 us; speedup vs baseline: 1.1642x; 1.1642x over previous
//
#include <hip/hip_runtime.h>

// Problem constants
#define DD 20          // hypervol spatial extent per axis
#define MM 32          // channel count m
#define OO 19          // output extent per axis (DD - RANK + 1, RANK=2)
#define NWIN (OO*OO*OO)                  // 6859 windows
#define WPB 4                            // windows per block (one per wave)
#define NBLK ((NWIN + WPB - 1) / WPB)    // 1715 blocks

// Lane tiling (phases 2/3): lane -> h = lane>>5 (j-half), i = lane&31 (own
// output channel), ib = lane&28 (i-quad base), qd = lane&3 (j-quad in half).
// Each lane owns a 4x4 tile: i' = ib+r (r=0..3), j' = h*16 + qd*4 + e (e=0..3).
// Tables stored so each (k,r) is one coalesced 1KB float4 load:
//   CS[k][r][lane][e] = cos(2*pi*k / (i'*32 + j' + 2))
//   PS[r][lane][e]    = P [i'][j']
//   MS[r][lane][e]    = Mw[i'][j'] / 16
#define CS_FLOATS (OO*MM*MM)             // 19456
#define PS_OFF CS_FLOATS                 // 19456 (= 19*1024)
#define MS_OFF (PS_OFF + MM*MM)          // 20480 (= 20*1024)
#define WS_FLOATS (MS_OFF + MM*MM)       // 21504

// per-wave LDS slice: S (640 floats) + X (608 floats)
#define LSLICE 1248
#define XOFF 640

__global__ __launch_bounds__(256) void build_tables_kernel(
        const float* __restrict__ Mw, const float* __restrict__ P,
        float* __restrict__ ws) {
    const int idx = blockIdx.x * 256 + threadIdx.x;
    if (idx >= WS_FLOATS) return;
    const int r10  = idx & 1023;         // PS_OFF/MS_OFF are multiples of 1024
    const int r    = r10 >> 8;
    const int lane = (r10 >> 2) & 63;
    const int e    = r10 & 3;
    const int ii   = (lane & 28) + r;
    const int jj   = ((lane >> 5) << 4) + (lane & 3) * 4 + e;
    if (idx < CS_FLOATS) {
        const int k = idx >> 10;
        ws[idx] = cosf(6.28318530717958647692f * (float)k
                       / (float)(ii * MM + jj + 2));
    } else if (idx < MS_OFF) {
        ws[idx] = P[ii * MM + jj];
    } else {
        ws[idx] = Mw[ii * MM + jj] * 0.0625f;
    }
}

// Wave-internal sync: LDS-counter drain only + compiler fence.
__device__ __forceinline__ void lds_sync() {
    __builtin_amdgcn_s_waitcnt(0xC07F);   // lgkmcnt(0) only
    __builtin_amdgcn_wave_barrier();
}

// DPP quad_perm helpers (VALU pipe, not LDS): 0xB1 = [1,0,3,2], 0x4E = [2,3,0,1]
template <int CTRL>
__device__ __forceinline__ float fdpp(float v) {
    return __int_as_float(__builtin_amdgcn_update_dpp(
        0, __float_as_int(v), CTRL, 0xF, 0xF, true));
}
__device__ __forceinline__ float quad_sum(float v) {
    v += fdpp<0xB1>(v);   // + lane^1
    v += fdpp<0x4E>(v);   // + lane^2
    return v;             // all 4 lanes of the quad hold the quad total
}

// One WAVE per (a,b,c) window; 4 independent windows per block.
// Phase 3: Chebyshev recurrence s_d = 2cosw*s_{d-1} - s_{d-2}, qp in init.
// SCHEDULING DISCIPLINE (R9 spilled 130MB of scratch by violating it):
//  - table loads sit immediately before their consuming phase, never before
//    phase 1 (in-flight float4 loads stack up past the 128-VGPR cap);
//  - phase 2/3 loops use limited unroll so the scheduler can't pipeline
//    20 ds_read_b128 results at once.
__global__ __launch_bounds__(256, 4) void spatial_kernel(
        const float* __restrict__ H, const float* __restrict__ ws,
        float* __restrict__ out) {
    __shared__ __align__(16) float sLDS[WPB][LSLICE];

    const int tid  = threadIdx.x;
    const int w    = tid >> 6;
    const int lane = tid & 63;
    const int i    = lane & 31;
    const int h    = lane >> 5;
    const int qd   = lane & 3;
    const int jb2  = (h << 4) + qd * 4;   // lane's j-quad base

    // XCD-contiguous block swizzle (1715 = 3*215 + 5*214, bijective)
    const int raw = blockIdx.x;
    const int xcd = raw & 7;
    const int k   = raw >> 3;
    const int sb  = (xcd < 3) ? (xcd * 215 + k) : (645 + (xcd - 3) * 214 + k);
    const int win = sb * WPB + w;
    if (win >= NWIN) return;             // wave-uniform; no block barriers exist
    const int c = win % OO;
    const int b = (win / OO) % OO;
    const int a = win / (OO * OO);

    const float4* __restrict__ T = (const float4*)ws;
    float* __restrict__ S = sLDS[w];          // phase-1 pre-sums (640 floats)
    float* __restrict__ X = sLDS[w] + XOFF;   // x rows           (608 floats)

    // ---- phase 1: 8-shift (a,b,c) pre-sum, 640 floats, float4 ----
    {
        float4 a0 = make_float4(0.f, 0.f, 0.f, 0.f);
        float4 a1 = a0, a2 = a0;
        #pragma unroll
        for (int da = 0; da < 2; ++da)
            #pragma unroll
            for (int db = 0; db < 2; ++db)
                #pragma unroll
                for (int dc = 0; dc < 2; ++dc) {
                    const float4* __restrict__ p = (const float4*)(
                        H + (size_t)((((a + da) * DD + (b + db)) * DD + (c + dc)) * DD) * MM);
                    const float4 v0 = p[lane];
                    const float4 v1 = p[64 + lane];
                    a0.x += v0.x; a0.y += v0.y; a0.z += v0.z; a0.w += v0.w;
                    a1.x += v1.x; a1.y += v1.y; a1.z += v1.z; a1.w += v1.w;
                    if (lane < 32) {
                        const float4 v2 = p[128 + lane];
                        a2.x += v2.x; a2.y += v2.y; a2.z += v2.z; a2.w += v2.w;
                    }
                }
        ((float4*)S)[lane]      = a0;
        ((float4*)S)[64 + lane] = a1;
        if (lane < 32) ((float4*)S)[128 + lane] = a2;
    }
    lds_sync();

    // ---- phase 2: y[d'] = S[d'] . (M/16) per 4x4 tile; x[d] = y[d]+y[d+1] ----
    // One ds_read_b128 per d' (8 distinct addrs/wave); quad combine via DPP.
    {
        float4 mt[4];                        // loaded HERE, not before phase 1
        #pragma unroll
        for (int r = 0; r < 4; ++r)
            mt[r] = T[(MS_OFF >> 2) + r * 64 + lane];

        float yprev = 0.f;
        #pragma unroll 2
        for (int dp = 0; dp < DD; ++dp) {
            const float4 sv = *(const float4*)(S + dp * MM + jb2);
            float p0 = sv.x*mt[0].x + sv.y*mt[0].y + sv.z*mt[0].z + sv.w*mt[0].w;
            float p1 = sv.x*mt[1].x + sv.y*mt[1].y + sv.z*mt[1].z + sv.w*mt[1].w;
            float p2 = sv.x*mt[2].x + sv.y*mt[2].y + sv.z*mt[2].z + sv.w*mt[2].w;
            float p3 = sv.x*mt[3].x + sv.y*mt[3].y + sv.z*mt[3].z + sv.w*mt[3].w;
            const float q0 = quad_sum(p0), q1 = quad_sum(p1);
            const float q2 = quad_sum(p2), q3 = quad_sum(p3);
            const float yv = (qd & 1) ? ((qd & 2) ? q3 : q1)
                                      : ((qd & 2) ? q2 : q0);   // this lane's i
            if (dp > 0) {
                float xd = yprev + yv;            // half-sum over lane's h
                xd += __shfl_xor(xd, 32, 64);     // combine halves
                if (h == 0) X[(dp - 1) * MM + i] = xd;
            }
            yprev = yv;
        }
    }
    lds_sync();

    // ---- phase 3: out[d][i] = sum_j x[d][j]*qp[i][j]*cos(w_ij*d) ----
    // Init loads HERE (R8 placement, spill-free). 48 persistent VGPRs.
    float4 s0[4], s1[4], t2c[4];
    #pragma unroll
    for (int r = 0; r < 4; ++r) {
        const float4 pv = T[(PS_OFF >> 2) + r * 64 + lane];
        const float4 va = T[(a * 4 + r) * 64 + lane];
        const float4 vb = T[(b * 4 + r) * 64 + lane];
        const float4 vc = T[(c * 4 + r) * 64 + lane];
        const float4 c1 = T[(1 * 4 + r) * 64 + lane];
        float4 qp;
        qp.x = pv.x * va.x * vb.x * vc.x;
        qp.y = pv.y * va.y * vb.y * vc.y;
        qp.z = pv.z * va.z * vb.z * vc.z;
        qp.w = pv.w * va.w * vb.w * vc.w;
        s1[r] = qp;
        s0[r] = make_float4(qp.x * c1.x, qp.y * c1.y, qp.z * c1.z, qp.w * c1.w);
        t2c[r] = make_float4(c1.x + c1.x, c1.y + c1.y, c1.z + c1.z, c1.w + c1.w);
    }
    const size_t obase = (size_t)win * (OO * MM);
    #pragma unroll 2
    for (int d = 0; d < OO; ++d) {
        const float4 xv = *(const float4*)(X + d * MM + jb2);   // 1 b128/lane
        float p0 = xv.x*s1[0].x + xv.y*s1[0].y + xv.z*s1[0].z + xv.w*s1[0].w;
        float p1 = xv.x*s1[1].x + xv.y*s1[1].y + xv.z*s1[1].z + xv.w*s1[1].w;
        float p2 = xv.x*s1[2].x + xv.y*s1[2].y + xv.z*s1[2].z + xv.w*s1[2].w;
        float p3 = xv.x*s1[3].x + xv.y*s1[3].y + xv.z*s1[3].z + xv.w*s1[3].w;
        #pragma unroll
        for (int r = 0; r < 4; ++r) {            // advance recurrence (16 FMA)
            float4 ns;
            ns.x = __builtin_fmaf(t2c[r].x, s1[r].x, -s0[r].x);
            ns.y = __builtin_fmaf(t2c[r].y, s1[r].y, -s0[r].y);
            ns.z = __builtin_fmaf(t2c[r].z, s1[r].z, -s0[r].z);
            ns.w = __builtin_fmaf(t2c[r].w, s1[r].w, -s0[r].w);
            s0[r] = s1[r];
            s1[r] = ns;
        }
        const float q0 = quad_sum(p0), q1 = quad_sum(p1);
        const float q2 = quad_sum(p2), q3 = quad_sum(p3);
        float t = (qd & 1) ? ((qd & 2) ? q3 : q1)
                           : ((qd & 2) ? q2 : q0);
        t += __shfl_xor(t, 32, 64);
        if (h == 0) out[obase + d * MM + i] = t;
    }
}

extern "C" void kernel_launch(void* const* d_in, const int* in_sizes, int n_in,
                              void* d_out, int out_size, void* d_ws, size_t ws_size,
                              hipStream_t stream) {
    const float* H  = (const float*)d_in[0];   // hypervol [20,20,20,20,32]
    const float* Mw = (const float*)d_in[1];   // M_w [32,32]
    const float* P  = (const float*)d_in[2];   // P   [32,32]
    float* out = (float*)d_out;
    float* ws  = (float*)d_ws;

    build_tables_kernel<<<(WS_FLOATS + 255) / 256, 256, 0, stream>>>(Mw, P, ws);
    spatial_kernel<<<NBLK, 256, 0, stream>>>(H, ws, out);
}

// Round 11
// 99.385 us; speedup vs baseline: 1.1999x; 1.0306x over previous
//
#include <hip/hip_runtime.h>

// Problem constants
#define DD 20          // hypervol spatial extent per axis
#define MM 32          // channel count m
#define OO 19          // output extent per axis (DD - RANK + 1, RANK=2)
#define NWIN (OO*OO*OO)                  // 6859 windows
#define WPB 2                            // windows per block (one per wave)
#define NBLK ((NWIN + WPB - 1) / WPB)    // 3430 blocks of 128 threads

// Lane tiling (phases 2/3): lane -> h = lane>>5 (j-half), i = lane&31 (own
// output channel), ib = lane&28 (i-quad base), qd = lane&3 (j-quad in half).
// Each lane owns a 4x4 tile: i' = ib+r (r=0..3), j' = h*16 + qd*4 + e (e=0..3).
// Tables stored so each (k,r) is one coalesced 1KB float4 load:
//   CS[k][r][lane][e] = cos(2*pi*k / (i'*32 + j' + 2))
//   PS[r][lane][e]    = P [i'][j']
//   MS[r][lane][e]    = Mw[i'][j'] / 16
#define CS_FLOATS (OO*MM*MM)             // 19456
#define PS_OFF CS_FLOATS                 // 19456 (= 19*1024)
#define MS_OFF (PS_OFF + MM*MM)          // 20480 (= 20*1024)
#define WS_FLOATS (MS_OFF + MM*MM)       // 21504

// per-wave LDS slice: S (640 floats) + X (608 floats)
#define LSLICE 1248
#define XOFF 640

__global__ __launch_bounds__(256) void build_tables_kernel(
        const float* __restrict__ Mw, const float* __restrict__ P,
        float* __restrict__ ws) {
    const int idx = blockIdx.x * 256 + threadIdx.x;
    if (idx >= WS_FLOATS) return;
    const int r10  = idx & 1023;         // PS_OFF/MS_OFF are multiples of 1024
    const int r    = r10 >> 8;
    const int lane = (r10 >> 2) & 63;
    const int e    = r10 & 3;
    const int ii   = (lane & 28) + r;
    const int jj   = ((lane >> 5) << 4) + (lane & 3) * 4 + e;
    if (idx < CS_FLOATS) {
        const int k = idx >> 10;
        ws[idx] = cosf(6.28318530717958647692f * (float)k
                       / (float)(ii * MM + jj + 2));
    } else if (idx < MS_OFF) {
        ws[idx] = P[ii * MM + jj];
    } else {
        ws[idx] = Mw[ii * MM + jj] * 0.0625f;
    }
}

// Wave-internal sync: LDS-counter drain only + compiler fence.
__device__ __forceinline__ void lds_sync() {
    __builtin_amdgcn_s_waitcnt(0xC07F);   // lgkmcnt(0) only
    __builtin_amdgcn_wave_barrier();
}

// DPP quad_perm helpers (VALU pipe, not LDS): 0xB1 = [1,0,3,2], 0x4E = [2,3,0,1]
template <int CTRL>
__device__ __forceinline__ float fdpp(float v) {
    return __int_as_float(__builtin_amdgcn_update_dpp(
        0, __float_as_int(v), CTRL, 0xF, 0xF, true));
}
__device__ __forceinline__ float quad_sum(float v) {
    v += fdpp<0xB1>(v);   // + lane^1
    v += fdpp<0x4E>(v);   // + lane^2
    return v;             // all 4 lanes of the quad hold the quad total
}

// One WAVE per (a,b,c) window; 2 windows per 128-thread block (fine-grained
// load balance: 3430 blocks ~ 13.4/CU). Phase 3: Chebyshev recurrence.
// SCHEDULING DISCIPLINE (R9 spilled 130MB violating it): table loads sit
// immediately before their consuming phase, never before phase 1.
// LATENCY DISCIPLINE (R10 lost 2x to exposed ds_read latency): phases 2/3
// use an explicit 2-deep software pipeline (prefetch row d+1 before
// consuming row d) with full unroll.
__global__ __launch_bounds__(128, 4) void spatial_kernel(
        const float* __restrict__ H, const float* __restrict__ ws,
        float* __restrict__ out) {
    __shared__ __align__(16) float sLDS[WPB][LSLICE];

    const int tid  = threadIdx.x;
    const int w    = tid >> 6;
    const int lane = tid & 63;
    const int i    = lane & 31;
    const int h    = lane >> 5;
    const int qd   = lane & 3;
    const int jb2  = (h << 4) + qd * 4;   // lane's j-quad base

    // XCD-contiguous block swizzle (3430 = 6*429 + 2*428, bijective)
    const int raw = blockIdx.x;
    const int xcd = raw & 7;
    const int k   = raw >> 3;
    const int sb  = (xcd < 6) ? (xcd * 429 + k) : (2574 + (xcd - 6) * 428 + k);
    const int win = sb * WPB + w;
    if (win >= NWIN) return;             // wave-uniform; no block barriers exist
    const int c = win % OO;
    const int b = (win / OO) % OO;
    const int a = win / (OO * OO);

    const float4* __restrict__ T = (const float4*)ws;
    float* __restrict__ S = sLDS[w];          // phase-1 pre-sums (640 floats)
    float* __restrict__ X = sLDS[w] + XOFF;   // x rows           (608 floats)

    // ---- phase 1: 8-shift (a,b,c) pre-sum, 640 floats, float4 ----
    {
        float4 a0 = make_float4(0.f, 0.f, 0.f, 0.f);
        float4 a1 = a0, a2 = a0;
        #pragma unroll
        for (int da = 0; da < 2; ++da)
            #pragma unroll
            for (int db = 0; db < 2; ++db)
                #pragma unroll
                for (int dc = 0; dc < 2; ++dc) {
                    const float4* __restrict__ p = (const float4*)(
                        H + (size_t)((((a + da) * DD + (b + db)) * DD + (c + dc)) * DD) * MM);
                    const float4 v0 = p[lane];
                    const float4 v1 = p[64 + lane];
                    a0.x += v0.x; a0.y += v0.y; a0.z += v0.z; a0.w += v0.w;
                    a1.x += v1.x; a1.y += v1.y; a1.z += v1.z; a1.w += v1.w;
                    if (lane < 32) {
                        const float4 v2 = p[128 + lane];
                        a2.x += v2.x; a2.y += v2.y; a2.z += v2.z; a2.w += v2.w;
                    }
                }
        ((float4*)S)[lane]      = a0;
        ((float4*)S)[64 + lane] = a1;
        if (lane < 32) ((float4*)S)[128 + lane] = a2;
    }
    lds_sync();

    // ---- phase 2: y[d'] = S[d'] . (M/16) per 4x4 tile; x[d] = y[d]+y[d+1] ----
    // 2-deep pipelined ds_read_b128; quad combine via DPP; halves via shfl.
    {
        float4 mt[4];                        // loaded HERE, not before phase 1
        #pragma unroll
        for (int r = 0; r < 4; ++r)
            mt[r] = T[(MS_OFF >> 2) + r * 64 + lane];

        float4 sv0 = *(const float4*)(S + 0 * MM + jb2);
        float4 sv  = *(const float4*)(S + 1 * MM + jb2);
        float yprev;
        {
            float p0 = sv0.x*mt[0].x + sv0.y*mt[0].y + sv0.z*mt[0].z + sv0.w*mt[0].w;
            float p1 = sv0.x*mt[1].x + sv0.y*mt[1].y + sv0.z*mt[1].z + sv0.w*mt[1].w;
            float p2 = sv0.x*mt[2].x + sv0.y*mt[2].y + sv0.z*mt[2].z + sv0.w*mt[2].w;
            float p3 = sv0.x*mt[3].x + sv0.y*mt[3].y + sv0.z*mt[3].z + sv0.w*mt[3].w;
            const float q0 = quad_sum(p0), q1 = quad_sum(p1);
            const float q2 = quad_sum(p2), q3 = quad_sum(p3);
            yprev = (qd & 1) ? ((qd & 2) ? q3 : q1)
                             : ((qd & 2) ? q2 : q0);
        }
        #pragma unroll
        for (int dp = 1; dp < DD; ++dp) {
            const float4 svn = (dp < DD - 1)
                ? *(const float4*)(S + (dp + 1) * MM + jb2) : sv;  // prefetch
            float p0 = sv.x*mt[0].x + sv.y*mt[0].y + sv.z*mt[0].z + sv.w*mt[0].w;
            float p1 = sv.x*mt[1].x + sv.y*mt[1].y + sv.z*mt[1].z + sv.w*mt[1].w;
            float p2 = sv.x*mt[2].x + sv.y*mt[2].y + sv.z*mt[2].z + sv.w*mt[2].w;
            float p3 = sv.x*mt[3].x + sv.y*mt[3].y + sv.z*mt[3].z + sv.w*mt[3].w;
            const float q0 = quad_sum(p0), q1 = quad_sum(p1);
            const float q2 = quad_sum(p2), q3 = quad_sum(p3);
            const float yv = (qd & 1) ? ((qd & 2) ? q3 : q1)
                                      : ((qd & 2) ? q2 : q0);
            float xd = yprev + yv;            // window sum over lane's h
            xd += __shfl_xor(xd, 32, 64);     // combine halves
            if (h == 0) X[(dp - 1) * MM + i] = xd;
            yprev = yv;
            sv = svn;
        }
    }
    lds_sync();

    // ---- phase 3: out[d][i] = sum_j x[d][j]*qp[i][j]*cos(w_ij*d) ----
    // Init loads HERE (R8/R10 placement, spill-free). 48 persistent VGPRs.
    float4 s0[4], s1[4], t2c[4];
    #pragma unroll
    for (int r = 0; r < 4; ++r) {
        const float4 pv = T[(PS_OFF >> 2) + r * 64 + lane];
        const float4 va = T[(a * 4 + r) * 64 + lane];
        const float4 vb = T[(b * 4 + r) * 64 + lane];
        const float4 vc = T[(c * 4 + r) * 64 + lane];
        const float4 c1 = T[(1 * 4 + r) * 64 + lane];
        float4 qp;
        qp.x = pv.x * va.x * vb.x * vc.x;
        qp.y = pv.y * va.y * vb.y * vc.y;
        qp.z = pv.z * va.z * vb.z * vc.z;
        qp.w = pv.w * va.w * vb.w * vc.w;
        s1[r] = qp;
        s0[r] = make_float4(qp.x * c1.x, qp.y * c1.y, qp.z * c1.z, qp.w * c1.w);
        t2c[r] = make_float4(c1.x + c1.x, c1.y + c1.y, c1.z + c1.z, c1.w + c1.w);
    }
    const size_t obase = (size_t)win * (OO * MM);
    float4 xv = *(const float4*)(X + 0 * MM + jb2);
    #pragma unroll
    for (int d = 0; d < OO; ++d) {
        const float4 xvn = (d < OO - 1)
            ? *(const float4*)(X + (d + 1) * MM + jb2) : xv;       // prefetch
        float p0 = xv.x*s1[0].x + xv.y*s1[0].y + xv.z*s1[0].z + xv.w*s1[0].w;
        float p1 = xv.x*s1[1].x + xv.y*s1[1].y + xv.z*s1[1].z + xv.w*s1[1].w;
        float p2 = xv.x*s1[2].x + xv.y*s1[2].y + xv.z*s1[2].z + xv.w*s1[2].w;
        float p3 = xv.x*s1[3].x + xv.y*s1[3].y + xv.z*s1[3].z + xv.w*s1[3].w;
        #pragma unroll
        for (int r = 0; r < 4; ++r) {            // advance recurrence (16 FMA)
            float4 ns;
            ns.x = __builtin_fmaf(t2c[r].x, s1[r].x, -s0[r].x);
            ns.y = __builtin_fmaf(t2c[r].y, s1[r].y, -s0[r].y);
            ns.z = __builtin_fmaf(t2c[r].z, s1[r].z, -s0[r].z);
            ns.w = __builtin_fmaf(t2c[r].w, s1[r].w, -s0[r].w);
            s0[r] = s1[r];
            s1[r] = ns;
        }
        const float q0 = quad_sum(p0), q1 = quad_sum(p1);
        const float q2 = quad_sum(p2), q3 = quad_sum(p3);
        float t = (qd & 1) ? ((qd & 2) ? q3 : q1)
                           : ((qd & 2) ? q2 : q0);
        t += __shfl_xor(t, 32, 64);
        if (h == 0) out[obase + d * MM + i] = t;
        xv = xvn;
    }
}

extern "C" void kernel_launch(void* const* d_in, const int* in_sizes, int n_in,
                              void* d_out, int out_size, void* d_ws, size_t ws_size,
                              hipStream_t stream) {
    const float* H  = (const float*)d_in[0];   // hypervol [20,20,20,20,32]
    const float* Mw = (const float*)d_in[1];   // M_w [32,32]
    const float* P  = (const float*)d_in[2];   // P   [32,32]
    float* out = (float*)d_out;
    float* ws  = (float*)d_ws;

    build_tables_kernel<<<(WS_FLOATS + 255) / 256, 256, 0, stream>>>(Mw, P, ws);
    spatial_kernel<<<NBLK, 128, 0, stream>>>(H, ws, out);
}

// Round 12
// 96.803 us; speedup vs baseline: 1.2319x; 1.0267x over previous
//
#include <hip/hip_runtime.h>

// Problem constants
#define DD 20          // hypervol spatial extent per axis
#define MM 32          // channel count m
#define OO 19          // output extent per axis (DD - RANK + 1, RANK=2)
#define NWIN (OO*OO*OO)                  // 6859 windows
#define WPB 4                            // windows per block (one per wave)
#define NBLK ((NWIN + WPB - 1) / WPB)    // 1715 blocks

// Lane mapping (R8, proven): lane -> (i = lane&31, h = lane>>5),
// lane's j-range = [h*16, h*16+16). Tables LANE-SWIZZLED so a wave's float4
// table read is one contiguous 1KB transaction:
//   CS[k][q][lane][e] = cos(2*pi*k / (i*32 + (h*16 + q*4 + e) + 2))
//   PS[q][lane][e]    = P [i][h*16 + q*4 + e]
//   MS[q][lane][e]    = Mw[i][h*16 + q*4 + e] / 16
#define CS_FLOATS (OO*MM*MM)             // 19456
#define PS_OFF CS_FLOATS                 // 19456
#define MS_OFF (PS_OFF + MM*MM)          // 20480
#define WS_FLOATS (MS_OFF + MM*MM)       // 21504

// per-wave LDS slice: S (640 floats); X (608) aliases S (forward overwrite)
#define LSLICE 640

__global__ __launch_bounds__(256) void build_tables_kernel(
        const float* __restrict__ Mw, const float* __restrict__ P,
        float* __restrict__ ws) {
    const int idx = blockIdx.x * 256 + threadIdx.x;
    if (idx >= WS_FLOATS) return;
    const int r10  = idx & 1023;         // PS_OFF/MS_OFF are multiples of 1024
    const int q    = r10 >> 8;
    const int lane = (r10 >> 2) & 63;
    const int e    = r10 & 3;
    const int i    = lane & 31;
    const int j    = ((lane >> 5) << 4) + q * 4 + e;
    if (idx < CS_FLOATS) {
        const int k = idx >> 10;
        ws[idx] = cosf(6.28318530717958647692f * (float)k
                       / (float)(i * MM + j + 2));
    } else if (idx < MS_OFF) {
        ws[idx] = P[i * MM + j];
    } else {
        ws[idx] = Mw[i * MM + j] * 0.0625f;
    }
}

// Wave-internal sync: LDS-counter drain only + compiler fence. No s_barrier,
// no vmcnt drain -> waves never convoy, global loads stay in flight.
__device__ __forceinline__ void lds_sync() {
    __builtin_amdgcn_s_waitcnt(0xC07F);   // lgkmcnt(0) only
    __builtin_amdgcn_wave_barrier();
}

// One WAVE per (a,b,c) window; 4 independent windows per block.
// Phase 3: Chebyshev recurrence s_d = 2cosw*s_{d-1} - s_{d-2}, qp in init.
// OCCUPANCY: (256,6) -> 6 waves/SIMD. Feasible only because phase 1 is
// batched (two 4-shift halves, sched_barrier between) so the in-flight
// global-load landing zone is ~10 dwordx4 instead of 20. R6's spill at
// (256,5) was driven by the fully-unrolled 20-load phase 1.
__global__ __launch_bounds__(256, 6) void spatial_kernel(
        const float* __restrict__ H, const float* __restrict__ ws,
        float* __restrict__ out) {
    __shared__ __align__(16) float sLDS[WPB][LSLICE];

    const int tid  = threadIdx.x;
    const int w    = tid >> 6;
    const int lane = tid & 63;
    const int i    = lane & 31;
    const int h    = lane >> 5;
    const int jb   = h * 16;

    // XCD-contiguous block swizzle (1715 = 3*215 + 5*214, bijective)
    const int raw = blockIdx.x;
    const int xcd = raw & 7;
    const int k   = raw >> 3;
    const int sb  = (xcd < 3) ? (xcd * 215 + k) : (645 + (xcd - 3) * 214 + k);
    const int win = sb * WPB + w;
    if (win >= NWIN) return;             // wave-uniform; no block barriers exist
    const int c = win % OO;
    const int b = (win / OO) % OO;
    const int a = win / (OO * OO);

    const float4* __restrict__ T = (const float4*)ws;
    float* __restrict__ S = sLDS[w];     // pre-sums; X aliases it (forward rows)
    float* __restrict__ X = sLDS[w];

    // ---- phase 1: 8-shift (a,b,c) pre-sum, 640 floats, float4, 2 batches ----
    {
        float4 a0 = make_float4(0.f, 0.f, 0.f, 0.f);
        float4 a1 = a0, a2 = a0;
        #pragma unroll
        for (int da = 0; da < 2; ++da) {
            #pragma unroll
            for (int db = 0; db < 2; ++db)
                #pragma unroll
                for (int dc = 0; dc < 2; ++dc) {
                    const float4* __restrict__ p = (const float4*)(
                        H + (size_t)((((a + da) * DD + (b + db)) * DD + (c + dc)) * DD) * MM);
                    const float4 v0 = p[lane];
                    const float4 v1 = p[64 + lane];
                    a0.x += v0.x; a0.y += v0.y; a0.z += v0.z; a0.w += v0.w;
                    a1.x += v1.x; a1.y += v1.y; a1.z += v1.z; a1.w += v1.w;
                    if (lane < 32) {
                        const float4 v2 = p[128 + lane];
                        a2.x += v2.x; a2.y += v2.y; a2.z += v2.z; a2.w += v2.w;
                    }
                }
            // fence between the two 4-shift batches: caps the in-flight
            // load landing zone (~10 dwordx4) so VGPR peak stays under the
            // 6-waves/EU budget
            __builtin_amdgcn_sched_barrier(0);
        }
        ((float4*)S)[lane]      = a0;
        ((float4*)S)[64 + lane] = a1;
        if (lane < 32) ((float4*)S)[128 + lane] = a2;
    }
    lds_sync();

    // ---- phase 2 (y-trick, no W buffer, no extra sync):
    //      y[d'] = dot(S[d'] half-row, Mw/16);  x[d] = y[d] + y[d+1] ----
    {
        float mt[16];                    // loaded HERE, not before phase 1
        #pragma unroll
        for (int q = 0; q < 4; ++q) {
            const float4 v = T[(MS_OFF >> 2) + q * 64 + lane];
            mt[q*4+0] = v.x; mt[q*4+1] = v.y; mt[q*4+2] = v.z; mt[q*4+3] = v.w;
        }
        float yprev;
        {
            const float4* __restrict__ sr = (const float4*)(S + 0 * MM + jb);
            float t = 0.f;
            #pragma unroll
            for (int q = 0; q < 4; ++q) {
                const float4 v = sr[q];
                t += v.x * mt[q*4+0] + v.y * mt[q*4+1]
                   + v.z * mt[q*4+2] + v.w * mt[q*4+3];
            }
            yprev = t;
        }
        #pragma unroll 4
        for (int dp = 1; dp < DD; ++dp) {
            const float4* __restrict__ sr = (const float4*)(S + dp * MM + jb);
            float t = 0.f;
            #pragma unroll
            for (int q = 0; q < 4; ++q) {
                const float4 v = sr[q];
                t += v.x * mt[q*4+0] + v.y * mt[q*4+1]
                   + v.z * mt[q*4+2] + v.w * mt[q*4+3];
            }
            float xd = yprev + t;             // window sum over lane's j-half
            xd += __shfl_xor(xd, 32, 64);     // combine halves
            if (h == 0) X[(dp - 1) * MM + i] = xd;  // overwrites dead S row
            yprev = t;
        }
    }
    lds_sync();

    // ---- phase 3: out[d][i] = sum_j x[d][j]*qp[i][j]*cos(w_ij*d) ----
    // Init loads HERE (R8 placement, spill-free). 48 persistent VGPRs.
    float s0[16], s1[16], t2c[16];
    #pragma unroll
    for (int q = 0; q < 4; ++q) {
        const float4 pv = T[(PS_OFF >> 2) + q * 64 + lane];
        const float4 va = T[(a * 4 + q) * 64 + lane];
        const float4 vb = T[(b * 4 + q) * 64 + lane];
        const float4 vc = T[(c * 4 + q) * 64 + lane];
        const float4 c1 = T[(1 * 4 + q) * 64 + lane];
        const float qpx = pv.x * va.x * vb.x * vc.x;
        const float qpy = pv.y * va.y * vb.y * vc.y;
        const float qpz = pv.z * va.z * vb.z * vc.z;
        const float qpw = pv.w * va.w * vb.w * vc.w;
        s1[q*4+0] = qpx; s0[q*4+0] = qpx * c1.x; t2c[q*4+0] = c1.x + c1.x;
        s1[q*4+1] = qpy; s0[q*4+1] = qpy * c1.y; t2c[q*4+1] = c1.y + c1.y;
        s1[q*4+2] = qpz; s0[q*4+2] = qpz * c1.z; t2c[q*4+2] = c1.z + c1.z;
        s1[q*4+3] = qpw; s0[q*4+3] = qpw * c1.w; t2c[q*4+3] = c1.w + c1.w;
    }
    const size_t obase = (size_t)win * (OO * MM);
    #pragma unroll 4
    for (int d = 0; d < OO; ++d) {
        const float4* __restrict__ xr = (const float4*)(X + d * MM + jb);
        float t = 0.f;
        #pragma unroll
        for (int q = 0; q < 4; ++q) {
            const float4 v = xr[q];
            t += v.x * s1[q*4+0] + v.y * s1[q*4+1]
               + v.z * s1[q*4+2] + v.w * s1[q*4+3];
        }
        #pragma unroll
        for (int jj = 0; jj < 16; ++jj) {     // advance recurrence
            const float nx = __builtin_fmaf(t2c[jj], s1[jj], -s0[jj]);
            s0[jj] = s1[jj];
            s1[jj] = nx;
        }
        t += __shfl_xor(t, 32, 64);
        if (h == 0) out[obase + d * MM + i] = t;
    }
}

extern "C" void kernel_launch(void* const* d_in, const int* in_sizes, int n_in,
                              void* d_out, int out_size, void* d_ws, size_t ws_size,
                              hipStream_t stream) {
    const float* H  = (const float*)d_in[0];   // hypervol [20,20,20,20,32]
    const float* Mw = (const float*)d_in[1];   // M_w [32,32]
    const float* P  = (const float*)d_in[2];   // P   [32,32]
    float* out = (float*)d_out;
    float* ws  = (float*)d_ws;

    build_tables_kernel<<<(WS_FLOATS + 255) / 256, 256, 0, stream>>>(Mw, P, ws);
    spatial_kernel<<<NBLK, 256, 0, stream>>>(H, ws, out);
}